// Round 5
// baseline (1090.553 us; speedup 1.0000x reference)
//
#include <hip/hip_runtime.h>

#define IN_C 64
#define OUT_C 128
#define HID 32
#define KNB 16
#define NEG 0.1f

__device__ __forceinline__ float leaky(float v, float s) { return fmaxf(v, s * v); }

// ---------------- K1: h = leaky(x @ W_in + b_in, 0.1)  [P,64]->[P,32] -------
// Block = 256 = 4 waves covers 128 points. Wave w: points (w>>1)*64+lane,
// channel half c0=(w&1)*16 -> c0 is wave-uniform, Win reads stay s_loads.
__global__ __launch_bounds__(256, 2) void hid_kernel(
    const float* __restrict__ x, const float* __restrict__ Win,
    const float* __restrict__ bin, float* __restrict__ h, int P)
{
    int lane = threadIdx.x & 63;
    int w    = threadIdx.x >> 6;
    int p    = blockIdx.x * 128 + (w >> 1) * 64 + lane;
    int c0   = (w & 1) * 16;
    if (p >= P) return;

    float xr[IN_C];
    const float4* x4 = (const float4*)(x + (long)p * IN_C);
    #pragma unroll
    for (int i = 0; i < IN_C / 4; ++i) {
        float4 v = x4[i];
        xr[4 * i + 0] = v.x; xr[4 * i + 1] = v.y;
        xr[4 * i + 2] = v.z; xr[4 * i + 3] = v.w;
    }

    float acc[16];
    #pragma unroll
    for (int c = 0; c < 16; ++c) acc[c] = bin[c0 + c];

    #pragma unroll 8
    for (int k = 0; k < IN_C; ++k) {
        float xv = xr[k];
        #pragma unroll
        for (int c = 0; c < 16; ++c) acc[c] = fmaf(xv, Win[k * HID + c0 + c], acc[c]);
    }

    float4* h4 = (float4*)(h + (long)p * HID + c0);
    #pragma unroll
    for (int c2 = 0; c2 < 4; ++c2) {
        float4 v;
        v.x = leaky(acc[4 * c2 + 0], NEG);
        v.y = leaky(acc[4 * c2 + 1], NEG);
        v.z = leaky(acc[4 * c2 + 2], NEG);
        v.w = leaky(acc[4 * c2 + 3], NEG);
        h4[c2] = v;
    }
}

// ---------------- K2: conv partials over 8 edges ----------------------------
// Block = 256 = 4 waves covers 128 points. Wave w: points (w>>1)*64+lane,
// edge half = w&1. Wa/ba/Wb/bb identical for all lanes -> s_loads.
// Inner body = exact R1 structure (h row loaded at loop top, scalar idx/pos
// prefetch only). Partials stored channel-major [half][c][P] -> coalesced.
__global__ __launch_bounds__(256, 2) void edge_kernel(
    const float* __restrict__ pos, const int* __restrict__ nbr,
    const float* __restrict__ h,
    const float* __restrict__ Wa, const float* __restrict__ ba,
    const float* __restrict__ Wb, const float* __restrict__ bb,
    float* __restrict__ convp, int N, int P)
{
    int lane = threadIdx.x & 63;
    int w    = threadIdx.x >> 6;
    int p    = blockIdx.x * 128 + (w >> 1) * 64 + lane;
    int half = w & 1;
    if (p >= P) return;
    long pbase = (p >= N) ? (long)N : 0;

    float px = pos[3L * p + 0];
    float py = pos[3L * p + 1];
    float pz = pos[3L * p + 2];

    float conv[HID];
    #pragma unroll
    for (int c = 0; c < HID; ++c) conv[c] = 0.f;

    const int* nrow = nbr + (long)p * KNB + half * 8;
    int  j = nrow[0];
    long q = pbase + j;
    float qx = pos[3 * q + 0], qy = pos[3 * q + 1], qz = pos[3 * q + 2];

    #pragma unroll 1
    for (int e = 0; e < 8; ++e) {
        // gathered h row for current edge (loads issue here, consumed below)
        float hgv[HID];
        const float4* h4 = (const float4*)(h + q * HID);
        #pragma unroll
        for (int i = 0; i < HID / 4; ++i) {
            float4 v = h4[i];
            hgv[4 * i + 0] = v.x; hgv[4 * i + 1] = v.y;
            hgv[4 * i + 2] = v.z; hgv[4 * i + 3] = v.w;
        }

        float rx = px - qx, ry = py - qy, rz = pz - qz;

        // scalar prefetch of next idx + neighbor pos (R1-proven pattern)
        if (e < 7) {
            j = nrow[e + 1];
            q = pbase + j;
            qx = pos[3 * q + 0]; qy = pos[3 * q + 1]; qz = pos[3 * q + 2];
        }

        float t[HID];
        #pragma unroll
        for (int c = 0; c < HID; ++c) {
            float v = fmaf(rx, Wa[c], fmaf(ry, Wa[HID + c], fmaf(rz, Wa[2 * HID + c], ba[c])));
            t[c] = leaky(v, NEG);
        }

        #pragma unroll
        for (int c = 0; c < HID; ++c) {
            float wv = bb[c];
            #pragma unroll
            for (int jj = 0; jj < HID; ++jj) wv = fmaf(t[jj], Wb[jj * HID + c], wv);
            conv[c] = fmaf(wv, hgv[c], conv[c]);
        }
    }

    // channel-major store: convp[(half*HID + c)*P + p] -- lane-coalesced
    float* cp = convp + (long)half * HID * P + p;
    #pragma unroll
    for (int c = 0; c < HID; ++c) cp[(long)c * P] = conv[c];
}

// ---------------- K3: out = leaky(conv@Wout + x@Wsc + bout + bsc, 0.01) -----
// Block = 256 = 4 waves covers 128 points. Wave w: points (w>>1)*64+lane,
// output half o0base=(w&1)*64 -> wave-uniform, Wout/Wsc stay s_loads.
__global__ __launch_bounds__(256, 2) void gemv_kernel(
    const float* __restrict__ x, const float* __restrict__ convp,
    const float* __restrict__ Wout, const float* __restrict__ bout,
    const float* __restrict__ Wsc, const float* __restrict__ bsc,
    float* __restrict__ out, int P)
{
    int lane   = threadIdx.x & 63;
    int w      = threadIdx.x >> 6;
    int p      = blockIdx.x * 128 + (w >> 1) * 64 + lane;
    int o0base = (w & 1) * 64;
    if (p >= P) return;

    // cv[c] = convp[0][c][p] + convp[1][c][p]  (channel-major, coalesced)
    float cv[HID];
    {
        const float* cp = convp + p;
        #pragma unroll
        for (int c = 0; c < HID; ++c)
            cv[c] = cp[(long)c * P] + cp[(long)(HID + c) * P];
    }

    float xr[IN_C];
    const float4* x4 = (const float4*)(x + (long)p * IN_C);
    #pragma unroll
    for (int i = 0; i < IN_C / 4; ++i) {
        float4 v = x4[i];
        xr[4 * i + 0] = v.x; xr[4 * i + 1] = v.y;
        xr[4 * i + 2] = v.z; xr[4 * i + 3] = v.w;
    }

    float* op = out + (long)p * OUT_C;
    #pragma unroll 1
    for (int chunk = 0; chunk < 8; ++chunk) {
        int o0 = o0base + chunk * 8;
        float a[8];
        #pragma unroll
        for (int l = 0; l < 8; ++l) a[l] = bout[o0 + l] + bsc[o0 + l];
        #pragma unroll
        for (int c = 0; c < HID; ++c) {
            float v = cv[c];
            const float* wr = Wout + c * OUT_C + o0;
            #pragma unroll
            for (int l = 0; l < 8; ++l) a[l] = fmaf(v, wr[l], a[l]);
        }
        #pragma unroll
        for (int k = 0; k < IN_C; ++k) {
            float v = xr[k];
            const float* wr = Wsc + k * OUT_C + o0;
            #pragma unroll
            for (int l = 0; l < 8; ++l) a[l] = fmaf(v, wr[l], a[l]);
        }
        float4 v0, v1;
        v0.x = leaky(a[0], 0.01f); v0.y = leaky(a[1], 0.01f);
        v0.z = leaky(a[2], 0.01f); v0.w = leaky(a[3], 0.01f);
        v1.x = leaky(a[4], 0.01f); v1.y = leaky(a[5], 0.01f);
        v1.z = leaky(a[6], 0.01f); v1.w = leaky(a[7], 0.01f);
        *(float4*)(op + o0 + 0) = v0;
        *(float4*)(op + o0 + 4) = v1;
    }
}

extern "C" void kernel_launch(void* const* d_in, const int* in_sizes, int n_in,
                              void* d_out, int out_size, void* d_ws, size_t ws_size,
                              hipStream_t stream) {
    const float* x    = (const float*)d_in[0];
    const float* pos  = (const float*)d_in[1];
    const int*   nbr  = (const int*)d_in[2];
    const float* Win  = (const float*)d_in[3];
    const float* bin  = (const float*)d_in[4];
    const float* Wa   = (const float*)d_in[5];
    const float* ba   = (const float*)d_in[6];
    const float* Wb   = (const float*)d_in[7];
    const float* bb   = (const float*)d_in[8];
    const float* Wout = (const float*)d_in[9];
    const float* bout = (const float*)d_in[10];
    const float* Wsc  = (const float*)d_in[11];
    const float* bsc  = (const float*)d_in[12];
    float* out = (float*)d_out;

    int P = in_sizes[0] / IN_C;   // B*N
    int N = P / 2;                // B = 2 per reference

    float* h     = (float*)d_ws;              // P*HID floats
    float* convp = h + (size_t)P * HID;       // 2*HID*P floats, channel-major

    int blocks = (P + 127) / 128;
    hid_kernel <<<blocks, 256, 0, stream>>>(x, Win, bin, h, P);
    edge_kernel<<<blocks, 256, 0, stream>>>(pos, nbr, h, Wa, ba, Wb, bb, convp, N, P);
    gemv_kernel<<<blocks, 256, 0, stream>>>(x, convp, Wout, bout, Wsc, bsc, out, P);
}

// Round 6
// 505.373 us; speedup vs baseline: 2.1579x; 2.1579x over previous
//
#include <hip/hip_runtime.h>

#define IN_C 64
#define OUT_C 128
#define HID 32
#define KNB 16
#define NEG 0.1f

__device__ __forceinline__ float leaky(float v, float s) { return fmaxf(v, s * v); }

// ---------------- K1: h = leaky(x @ W_in + b_in, 0.1)  [P,64]->[P,32] -------
// One lane per point; all weight addresses wave-uniform -> s_load broadcasts.
// (unchanged from R1)
__global__ __launch_bounds__(256) void hid_kernel(
    const float* __restrict__ x, const float* __restrict__ Win,
    const float* __restrict__ bin, float* __restrict__ h, int P)
{
    int p = blockIdx.x * blockDim.x + threadIdx.x;
    if (p >= P) return;

    float xr[IN_C];
    const float4* x4 = (const float4*)(x + (long)p * IN_C);
    #pragma unroll
    for (int i = 0; i < IN_C / 4; ++i) {
        float4 v = x4[i];
        xr[4 * i + 0] = v.x; xr[4 * i + 1] = v.y;
        xr[4 * i + 2] = v.z; xr[4 * i + 3] = v.w;
    }

    float acc[HID];
    #pragma unroll
    for (int c = 0; c < HID; ++c) acc[c] = bin[c];

    #pragma unroll 8
    for (int k = 0; k < IN_C; ++k) {
        float xv = xr[k];
        #pragma unroll
        for (int c = 0; c < HID; ++c) acc[c] = fmaf(xv, Win[k * HID + c], acc[c]);
    }

    float4* h4 = (float4*)(h + (long)p * HID);
    #pragma unroll
    for (int c2 = 0; c2 < HID / 4; ++c2) {
        float4 v;
        v.x = leaky(acc[4 * c2 + 0], NEG);
        v.y = leaky(acc[4 * c2 + 1], NEG);
        v.z = leaky(acc[4 * c2 + 2], NEG);
        v.w = leaky(acc[4 * c2 + 3], NEG);
        h4[c2] = v;
    }
}

// ---------------- K2: monolithic per-point kernel (R1 + dep-chain fix) ------
// One thread per point, exact R1 memory structure. ONLY change: the 32x32
// edge GEMM is loop-swapped to accumulator form in 16-channel blocks, so no
// serial FMA dependency chain (dep distance 16 insts >> 4cy fma latency).
__global__ __launch_bounds__(256, 1) void point_kernel(
    const float* __restrict__ x, const float* __restrict__ pos,
    const int* __restrict__ nbr, const float* __restrict__ h,
    const float* __restrict__ Wa, const float* __restrict__ ba,
    const float* __restrict__ Wb, const float* __restrict__ bb,
    const float* __restrict__ Wout, const float* __restrict__ bout,
    const float* __restrict__ Wsc, const float* __restrict__ bsc,
    float* __restrict__ out, int N, int P)
{
    int p = blockIdx.x * blockDim.x + threadIdx.x;
    if (p >= P) return;
    long pbase = (p >= N) ? (long)N : 0;   // per-batch index base (B=2)

    float px = pos[3L * p + 0];
    float py = pos[3L * p + 1];
    float pz = pos[3L * p + 2];

    float conv[HID];
    #pragma unroll
    for (int c = 0; c < HID; ++c) conv[c] = 0.f;

    const int* nrow = nbr + (long)p * KNB;
    int  j = nrow[0];
    long q = pbase + j;
    float qx = pos[3 * q + 0], qy = pos[3 * q + 1], qz = pos[3 * q + 2];

    #pragma unroll 1
    for (int e = 0; e < KNB; ++e) {
        // gathered h row for current edge (issues here, consumed after t-MLP)
        float hg[HID];
        const float4* h4 = (const float4*)(h + q * HID);
        #pragma unroll
        for (int i = 0; i < HID / 4; ++i) {
            float4 v = h4[i];
            hg[4 * i + 0] = v.x; hg[4 * i + 1] = v.y;
            hg[4 * i + 2] = v.z; hg[4 * i + 3] = v.w;
        }

        float rx = px - qx, ry = py - qy, rz = pz - qz;

        // scalar prefetch of next idx + neighbor pos (R1-proven pattern)
        if (e < KNB - 1) {
            j = nrow[e + 1];
            q = pbase + j;
            qx = pos[3 * q + 0]; qy = pos[3 * q + 1]; qz = pos[3 * q + 2];
        }

        // t = leaky(rel @ Wa + ba, 0.1): 3-term chains, independent across c
        float t[HID];
        #pragma unroll
        for (int c = 0; c < HID; ++c) {
            float v = fmaf(rx, Wa[c], fmaf(ry, Wa[HID + c], fmaf(rz, Wa[2 * HID + c], ba[c])));
            t[c] = leaky(v, NEG);
        }

        // w = t @ Wb + bb in ACCUMULATOR form, 16 channels per block:
        // each w[i] updated once per 16 FMAs -> no latency-bound chain.
        #pragma unroll
        for (int cb = 0; cb < HID; cb += 16) {
            float wacc[16];
            #pragma unroll
            for (int i = 0; i < 16; ++i) wacc[i] = bb[cb + i];
            #pragma unroll
            for (int jj = 0; jj < HID; ++jj) {
                float tj = t[jj];
                const float* wr = Wb + jj * HID + cb;
                #pragma unroll
                for (int i = 0; i < 16; ++i) wacc[i] = fmaf(tj, wr[i], wacc[i]);
            }
            #pragma unroll
            for (int i = 0; i < 16; ++i)
                conv[cb + i] = fmaf(wacc[i], hg[cb + i], conv[cb + i]);
        }
    }

    // ---- GEMV: out = leaky(conv@Wout + x@Wsc + bout + bsc, 0.01) ----
    // x row loaded here (not held across the edge loop) to cap register peak.
    float xr[IN_C];
    const float4* x4 = (const float4*)(x + (long)p * IN_C);
    #pragma unroll
    for (int i = 0; i < IN_C / 4; ++i) {
        float4 v = x4[i];
        xr[4 * i + 0] = v.x; xr[4 * i + 1] = v.y;
        xr[4 * i + 2] = v.z; xr[4 * i + 3] = v.w;
    }

    float* op = out + (long)p * OUT_C;
    #pragma unroll 1
    for (int chunk = 0; chunk < OUT_C / 8; ++chunk) {
        int o0 = chunk * 8;
        float a[8];
        #pragma unroll
        for (int l = 0; l < 8; ++l) a[l] = bout[o0 + l] + bsc[o0 + l];
        #pragma unroll
        for (int c = 0; c < HID; ++c) {
            float v = conv[c];
            const float* wr = Wout + c * OUT_C + o0;
            #pragma unroll
            for (int l = 0; l < 8; ++l) a[l] = fmaf(v, wr[l], a[l]);
        }
        #pragma unroll
        for (int k = 0; k < IN_C; ++k) {
            float v = xr[k];
            const float* wr = Wsc + k * OUT_C + o0;
            #pragma unroll
            for (int l = 0; l < 8; ++l) a[l] = fmaf(v, wr[l], a[l]);
        }
        float4 v0, v1;
        v0.x = leaky(a[0], 0.01f); v0.y = leaky(a[1], 0.01f);
        v0.z = leaky(a[2], 0.01f); v0.w = leaky(a[3], 0.01f);
        v1.x = leaky(a[4], 0.01f); v1.y = leaky(a[5], 0.01f);
        v1.z = leaky(a[6], 0.01f); v1.w = leaky(a[7], 0.01f);
        *(float4*)(op + o0 + 0) = v0;
        *(float4*)(op + o0 + 4) = v1;
    }
}

extern "C" void kernel_launch(void* const* d_in, const int* in_sizes, int n_in,
                              void* d_out, int out_size, void* d_ws, size_t ws_size,
                              hipStream_t stream) {
    const float* x    = (const float*)d_in[0];
    const float* pos  = (const float*)d_in[1];
    const int*   nbr  = (const int*)d_in[2];
    const float* Win  = (const float*)d_in[3];
    const float* bin  = (const float*)d_in[4];
    const float* Wa   = (const float*)d_in[5];
    const float* ba   = (const float*)d_in[6];
    const float* Wb   = (const float*)d_in[7];
    const float* bb   = (const float*)d_in[8];
    const float* Wout = (const float*)d_in[9];
    const float* bout = (const float*)d_in[10];
    const float* Wsc  = (const float*)d_in[11];
    const float* bsc  = (const float*)d_in[12];
    float* out = (float*)d_out;

    int P = in_sizes[0] / IN_C;   // B*N
    int N = P / 2;                // B = 2 per reference
    float* h = (float*)d_ws;      // P*HID floats

    hid_kernel<<<(P + 255) / 256, 256, 0, stream>>>(x, Win, bin, h, P);
    point_kernel<<<(P + 255) / 256, 256, 0, stream>>>(
        x, pos, nbr, h, Wa, ba, Wb, bb, Wout, bout, Wsc, bsc, out, N, P);
}

// Round 7
// 81.411 us; speedup vs baseline: 13.3957x; 6.2077x over previous
//
#include <hip/hip_runtime.h>
#include <hip/hip_bf16.h>

#define IN_C 64
#define OUT_C 128
#define HID 32
#define KNB 16

typedef __attribute__((ext_vector_type(8))) short short8;
typedef __attribute__((ext_vector_type(4))) float f32x4;

__device__ __forceinline__ float leaky(float v, float s) { return fmaxf(v, s * v); }

__device__ __forceinline__ short bf16s(float f) {
    __hip_bfloat16 h = __float2bfloat16(f);
    return *reinterpret_cast<short*>(&h);
}

// ---------------- K1: h = leaky(x @ W_in + b_in, 0.1) via MFMA --------------
// Wave handles 16 points. A = x[16 rows x 64 k] (2 k-steps), B = Win (2 n-tiles),
// B-frags register-preloaded (loop-invariant, 16 VGPR). D: row=4g+r -> point,
// col=n -> channel.
__global__ __launch_bounds__(256) void hid_mfma(
    const float* __restrict__ x, const float* __restrict__ Win,
    const float* __restrict__ bin, float* __restrict__ h, int P)
{
    int lane = threadIdx.x & 63;
    int widx = __builtin_amdgcn_readfirstlane(threadIdx.x >> 6);
    int wavebase = (blockIdx.x * 4 + widx) * 16;
    if (wavebase >= P) return;
    int n = lane & 15, g = lane >> 4;

    // B-frags: bfr[ks][nt][e] = Win[ks*32 + 8g + e][nt*16 + n]
    short8 bfr[2][2];
    #pragma unroll
    for (int ks = 0; ks < 2; ++ks)
        #pragma unroll
        for (int nt = 0; nt < 2; ++nt)
            #pragma unroll
            for (int e = 0; e < 8; ++e)
                bfr[ks][nt][e] = bf16s(Win[(ks * 32 + 8 * g + e) * HID + nt * 16 + n]);

    float bv0 = bin[n], bv1 = bin[16 + n];

    // A-frags: row = n (point in group), k = 8g+e per 32-k step
    const float* xr = x + (long)(wavebase + n) * IN_C;
    short8 a[2];
    #pragma unroll
    for (int ks = 0; ks < 2; ++ks) {
        float4 v0 = *(const float4*)(xr + ks * 32 + 8 * g);
        float4 v1 = *(const float4*)(xr + ks * 32 + 8 * g + 4);
        a[ks][0] = bf16s(v0.x); a[ks][1] = bf16s(v0.y);
        a[ks][2] = bf16s(v0.z); a[ks][3] = bf16s(v0.w);
        a[ks][4] = bf16s(v1.x); a[ks][5] = bf16s(v1.y);
        a[ks][6] = bf16s(v1.z); a[ks][7] = bf16s(v1.w);
    }

    #pragma unroll
    for (int nt = 0; nt < 2; ++nt) {
        float bv = nt ? bv1 : bv0;
        f32x4 acc = { bv, bv, bv, bv };
        acc = __builtin_amdgcn_mfma_f32_16x16x32_bf16(a[0], bfr[0][nt], acc, 0, 0, 0);
        acc = __builtin_amdgcn_mfma_f32_16x16x32_bf16(a[1], bfr[1][nt], acc, 0, 0, 0);
        #pragma unroll
        for (int r = 0; r < 4; ++r)
            h[(long)(wavebase + 4 * g + r) * HID + nt * 16 + n] = leaky(acc[r], 0.1f);
    }
}

// ---------------- K2: edge phase + output GEMV, fused, MFMA ------------------
// Block = 4 independent waves; each wave owns 16 points.
// Edge phase per point: A = t[16 edges x 32 k] built in-register from rel@Wa,
// B = Wb (2 n-halves, register frags), D = w[16 edges x 32 ch]; conv[c] =
// sum_e w[e][c]*h[q_e][c] via in-lane dot (4 rows) + shfl_xor(16,32) reduce.
// conv -> transposed padded LDS (cbuf[c][pt], stride 17: conflict-free).
// GEMV: A = [16 pts x 96 k] = conv(LDS) || x(global), B = [Wout;Wsc] bf16
// packed in LDS (swizzled chunks, <=2-way), 3 k-steps x 8 n-tiles = 24 MFMA.
__global__ __launch_bounds__(256) void edgeout_mfma(
    const float* __restrict__ x, const float* __restrict__ pos,
    const int* __restrict__ nbr, const float* __restrict__ h,
    const float* __restrict__ Wa, const float* __restrict__ ba,
    const float* __restrict__ Wb, const float* __restrict__ bb,
    const float* __restrict__ Wout, const float* __restrict__ bout,
    const float* __restrict__ Wsc, const float* __restrict__ bsc,
    float* __restrict__ out, int N, int P)
{
    __shared__ short bpk[1536 * 8];        // 24 KB: [Wout;Wsc] bf16 chunks
    __shared__ float cbuf[4][32 * 17];     // 8.5 KB: per-wave conv, transposed

    int tid = threadIdx.x;

    // ---- one-time B-pack: Bw[96][128] rows 0-31=Wout, 32-95=Wsc ----
    for (int c = tid; c < 1536; c += 256) {
        int ks = c >> 9;            // k-step 0..2
        int rem = c & 511;
        int nt = rem >> 6;          // n-tile 0..7
        int nn = (rem >> 2) & 15;   // col within tile
        int g  = rem & 3;           // lane-group
        int col = nt * 16 + nn;
        short8 v;
        #pragma unroll
        for (int e = 0; e < 8; ++e) {
            int row = ks * 32 + 8 * g + e;
            float f = (row < 32) ? Wout[row * OUT_C + col]
                                 : Wsc[(row - 32) * OUT_C + col];
            v[e] = bf16s(f);
        }
        int s = (g + (nn >> 1)) & 3;   // bank-rotation swizzle
        *(short8*)&bpk[(((ks * 8 + nt) * 64) + nn * 4 + s) * 8] = v;
    }
    __syncthreads();

    int lane = tid & 63;
    int widx = __builtin_amdgcn_readfirstlane(tid >> 6);
    int n = lane & 15, g = lane >> 4;
    int wavebase = (blockIdx.x * 4 + widx) * 16;
    if (wavebase >= P) return;

    // ---- loop-invariant per-lane preloads ----
    float waX[8], waY[8], waZ[8], bav[8];
    #pragma unroll
    for (int e = 0; e < 8; ++e) {
        int k = 8 * g + e;
        waX[e] = Wa[k]; waY[e] = Wa[HID + k]; waZ[e] = Wa[2 * HID + k];
        bav[e] = ba[k];
    }
    short8 wb0, wb1;
    #pragma unroll
    for (int e = 0; e < 8; ++e) {
        int k = 8 * g + e;
        wb0[e] = bf16s(Wb[k * HID + n]);
        wb1[e] = bf16s(Wb[k * HID + 16 + n]);
    }
    float bb0 = bb[n], bb1 = bb[16 + n];
    float* cb = cbuf[widx];

    // ---- edge phase: 16 points sequentially ----
    #pragma unroll 1
    for (int pt = 0; pt < 16; ++pt) {
        int p = wavebase + pt;
        long pbase = (p >= N) ? (long)N : 0;
        float px = pos[3L * p], py = pos[3L * p + 1], pz = pos[3L * p + 2];

        const int* nrow = nbr + (long)p * KNB;
        // t-row edge (row = n)
        long qt = pbase + nrow[n];
        float rx = px - pos[3 * qt], ry = py - pos[3 * qt + 1], rz = pz - pos[3 * qt + 2];

        // hg rows (D rows 4g+r)
        long q0 = pbase + nrow[4 * g + 0];
        long q1 = pbase + nrow[4 * g + 1];
        long q2 = pbase + nrow[4 * g + 2];
        long q3 = pbase + nrow[4 * g + 3];
        float hA0 = h[q0 * HID + n],      hB0 = h[q0 * HID + 16 + n];
        float hA1 = h[q1 * HID + n],      hB1 = h[q1 * HID + 16 + n];
        float hA2 = h[q2 * HID + n],      hB2 = h[q2 * HID + 16 + n];
        float hA3 = h[q3 * HID + n],      hB3 = h[q3 * HID + 16 + n];

        // t = leaky(rel @ Wa + ba, 0.1) for this lane's 8 k-slots
        short8 af;
        #pragma unroll
        for (int e = 0; e < 8; ++e) {
            float tv = fmaf(rx, waX[e], fmaf(ry, waY[e], fmaf(rz, waZ[e], bav[e])));
            af[e] = bf16s(leaky(tv, 0.1f));
        }

        f32x4 w0 = { bb0, bb0, bb0, bb0 };
        f32x4 w1 = { bb1, bb1, bb1, bb1 };
        w0 = __builtin_amdgcn_mfma_f32_16x16x32_bf16(af, wb0, w0, 0, 0, 0);
        w1 = __builtin_amdgcn_mfma_f32_16x16x32_bf16(af, wb1, w1, 0, 0, 0);

        // conv partial: dot over this lane's 4 edge-rows
        float pa = w0[0] * hA0 + w0[1] * hA1 + w0[2] * hA2 + w0[3] * hA3;
        float pb = w1[0] * hB0 + w1[1] * hB1 + w1[2] * hB2 + w1[3] * hB3;
        // reduce across the 4 lane-groups (rows 0-15)
        pa += __shfl_xor(pa, 16, 64);  pa += __shfl_xor(pa, 32, 64);
        pb += __shfl_xor(pb, 16, 64);  pb += __shfl_xor(pb, 32, 64);

        if (lane < 16) {
            cb[lane * 17 + pt]        = pa;   // conv[c=lane][pt]
            cb[(lane + 16) * 17 + pt] = pb;   // conv[c=lane+16][pt]
        }
    }
    asm volatile("s_waitcnt lgkmcnt(0)" ::: "memory");

    // ---- GEMV phase ----
    // A-frags: row = n (point), k-slots 8g+e per 32-k step
    short8 a0, a1, a2;
    #pragma unroll
    for (int e = 0; e < 8; ++e)
        a0[e] = bf16s(cb[(8 * g + e) * 17 + n]);   // conv channels (k-step 0)
    {
        const float* xr = x + (long)(wavebase + n) * IN_C;
        float4 v0 = *(const float4*)(xr + 8 * g);
        float4 v1 = *(const float4*)(xr + 8 * g + 4);
        float4 v2 = *(const float4*)(xr + 32 + 8 * g);
        float4 v3 = *(const float4*)(xr + 32 + 8 * g + 4);
        a1[0] = bf16s(v0.x); a1[1] = bf16s(v0.y); a1[2] = bf16s(v0.z); a1[3] = bf16s(v0.w);
        a1[4] = bf16s(v1.x); a1[5] = bf16s(v1.y); a1[6] = bf16s(v1.z); a1[7] = bf16s(v1.w);
        a2[0] = bf16s(v2.x); a2[1] = bf16s(v2.y); a2[2] = bf16s(v2.z); a2[3] = bf16s(v2.w);
        a2[4] = bf16s(v3.x); a2[5] = bf16s(v3.y); a2[6] = bf16s(v3.z); a2[7] = bf16s(v3.w);
    }

    int s = (g + (n >> 1)) & 3;
    #pragma unroll 1
    for (int nt = 0; nt < 8; ++nt) {
        short8 b0 = *(short8*)&bpk[(((0 * 8 + nt) * 64) + n * 4 + s) * 8];
        short8 b1 = *(short8*)&bpk[(((1 * 8 + nt) * 64) + n * 4 + s) * 8];
        short8 b2 = *(short8*)&bpk[(((2 * 8 + nt) * 64) + n * 4 + s) * 8];
        int o = nt * 16 + n;
        float bv = bout[o] + bsc[o];
        f32x4 acc = { bv, bv, bv, bv };
        acc = __builtin_amdgcn_mfma_f32_16x16x32_bf16(a0, b0, acc, 0, 0, 0);
        acc = __builtin_amdgcn_mfma_f32_16x16x32_bf16(a1, b1, acc, 0, 0, 0);
        acc = __builtin_amdgcn_mfma_f32_16x16x32_bf16(a2, b2, acc, 0, 0, 0);
        #pragma unroll
        for (int r = 0; r < 4; ++r)
            out[(long)(wavebase + 4 * g + r) * OUT_C + o] = leaky(acc[r], 0.01f);
    }
}

extern "C" void kernel_launch(void* const* d_in, const int* in_sizes, int n_in,
                              void* d_out, int out_size, void* d_ws, size_t ws_size,
                              hipStream_t stream) {
    const float* x    = (const float*)d_in[0];
    const float* pos  = (const float*)d_in[1];
    const int*   nbr  = (const int*)d_in[2];
    const float* Win  = (const float*)d_in[3];
    const float* bin  = (const float*)d_in[4];
    const float* Wa   = (const float*)d_in[5];
    const float* ba   = (const float*)d_in[6];
    const float* Wb   = (const float*)d_in[7];
    const float* bb   = (const float*)d_in[8];
    const float* Wout = (const float*)d_in[9];
    const float* bout = (const float*)d_in[10];
    const float* Wsc  = (const float*)d_in[11];
    const float* bsc  = (const float*)d_in[12];
    float* out = (float*)d_out;

    int P = in_sizes[0] / IN_C;   // B*N = 131072
    int N = P / 2;                // B = 2 per reference
    float* h = (float*)d_ws;      // P*HID floats = 16.8 MB

    int blocks = (P + 63) / 64;   // 64 points per block (4 waves x 16)
    hid_mfma<<<blocks, 256, 0, stream>>>(x, Win, bin, h, P);
    edgeout_mfma<<<blocks, 256, 0, stream>>>(
        x, pos, nbr, h, Wa, ba, Wb, bb, Wout, bout, Wsc, bsc, out, N, P);
}

// Round 8
// 74.679 us; speedup vs baseline: 14.6032x; 1.0901x over previous
//
#include <hip/hip_runtime.h>
#include <hip/hip_bf16.h>

#define IN_C 64
#define OUT_C 128
#define HID 32
#define KNB 16

typedef __attribute__((ext_vector_type(8))) short short8;
typedef __attribute__((ext_vector_type(4))) float f32x4;

__device__ __forceinline__ float leaky(float v, float s) { return fmaxf(v, s * v); }

__device__ __forceinline__ unsigned bf16u(float f) {
    __hip_bfloat16 h = __float2bfloat16(f);
    return (unsigned)*reinterpret_cast<unsigned short*>(&h);
}
__device__ __forceinline__ short bf16s(float f) {
    __hip_bfloat16 h = __float2bfloat16(f);
    return *reinterpret_cast<short*>(&h);
}

// ---------------- K0: one-time packs ----------------------------------------
// pk: [Wout;Wsc] (96x128) -> bf16 chunks, lane-linear: chunk c = (ks*8+nt)*64
//     + g*16 + n holds Bw[ks*32+8g+e][nt*16+n] for e=0..7. 24 KB, L2-resident.
// pos4: [P] float4 copy of pos rows (1 dwordx4 per gather instead of 3 dwords).
__global__ __launch_bounds__(256) void pack_kernel(
    const float* __restrict__ pos, const float* __restrict__ Wout,
    const float* __restrict__ Wsc, float4* __restrict__ pos4,
    short* __restrict__ pk, int P)
{
    int t = blockIdx.x * 256 + threadIdx.x;
    if (t < 1536) {
        int ks = t >> 9, rem = t & 511;
        int nt = rem >> 6, g = (rem >> 4) & 3, n = rem & 15;
        int col = nt * 16 + n;
        short8 v;
        #pragma unroll
        for (int e = 0; e < 8; ++e) {
            int row = ks * 32 + 8 * g + e;
            float f = (row < 32) ? Wout[row * OUT_C + col]
                                 : Wsc[(row - 32) * OUT_C + col];
            v[e] = bf16s(f);
        }
        *(short8*)(pk + (long)t * 8) = v;
    }
    if (t < P) {
        float4 v;
        v.x = pos[3L * t + 0]; v.y = pos[3L * t + 1];
        v.z = pos[3L * t + 2]; v.w = 0.f;
        pos4[t] = v;
    }
}

// ---------------- K1: h2 = packed bf16 pair of leaky(x @ W_in + b_in) -------
// Wave handles 16 points. h2[p][n] = (bf16 h[p][16+n] << 16) | bf16 h[p][n].
__global__ __launch_bounds__(256) void hid_mfma(
    const float* __restrict__ x, const float* __restrict__ Win,
    const float* __restrict__ bin, unsigned* __restrict__ h2, int P)
{
    int lane = threadIdx.x & 63;
    int widx = __builtin_amdgcn_readfirstlane(threadIdx.x >> 6);
    int wavebase = (blockIdx.x * 4 + widx) * 16;
    if (wavebase >= P) return;
    int n = lane & 15, g = lane >> 4;

    short8 bfr[2][2];
    #pragma unroll
    for (int ks = 0; ks < 2; ++ks)
        #pragma unroll
        for (int nt = 0; nt < 2; ++nt)
            #pragma unroll
            for (int e = 0; e < 8; ++e)
                bfr[ks][nt][e] = bf16s(Win[(ks * 32 + 8 * g + e) * HID + nt * 16 + n]);

    float bv0 = bin[n], bv1 = bin[16 + n];

    const float* xr = x + (long)(wavebase + n) * IN_C;
    short8 a[2];
    #pragma unroll
    for (int ks = 0; ks < 2; ++ks) {
        float4 v0 = *(const float4*)(xr + ks * 32 + 8 * g);
        float4 v1 = *(const float4*)(xr + ks * 32 + 8 * g + 4);
        a[ks][0] = bf16s(v0.x); a[ks][1] = bf16s(v0.y);
        a[ks][2] = bf16s(v0.z); a[ks][3] = bf16s(v0.w);
        a[ks][4] = bf16s(v1.x); a[ks][5] = bf16s(v1.y);
        a[ks][6] = bf16s(v1.z); a[ks][7] = bf16s(v1.w);
    }

    f32x4 acc0 = { bv0, bv0, bv0, bv0 };
    f32x4 acc1 = { bv1, bv1, bv1, bv1 };
    acc0 = __builtin_amdgcn_mfma_f32_16x16x32_bf16(a[0], bfr[0][0], acc0, 0, 0, 0);
    acc0 = __builtin_amdgcn_mfma_f32_16x16x32_bf16(a[1], bfr[1][0], acc0, 0, 0, 0);
    acc1 = __builtin_amdgcn_mfma_f32_16x16x32_bf16(a[0], bfr[0][1], acc1, 0, 0, 0);
    acc1 = __builtin_amdgcn_mfma_f32_16x16x32_bf16(a[1], bfr[1][1], acc1, 0, 0, 0);

    #pragma unroll
    for (int r = 0; r < 4; ++r) {
        unsigned lo = bf16u(leaky(acc0[r], 0.1f));
        unsigned hi = bf16u(leaky(acc1[r], 0.1f));
        h2[(long)(wavebase + 4 * g + r) * 16 + n] = (hi << 16) | lo;
    }
}

// ---------------- K2: edge phase + output GEMV, fused, MFMA ------------------
// Block = 4 independent waves; each wave owns 16 points. No __syncthreads.
// Edge phase per point: A = t[16 edges x 32 k] (built in-register from rel@Wa),
// B = Wb register frags, D = w[16 edges x 32 ch]; conv via in-lane dot over 4
// rows + shfl_xor(16,32) reduce -> per-wave transposed LDS (stride 17).
// GEMV: A = [16 pts x 96 k] = conv(LDS) || x(global); B-frags loaded straight
// from the global bf16 pack pk (coalesced dwordx4, L2-hot).
__global__ __launch_bounds__(256) void edgeout_mfma(
    const float* __restrict__ x, const float4* __restrict__ pos4,
    const int* __restrict__ nbr, const unsigned* __restrict__ h2,
    const float* __restrict__ Wa, const float* __restrict__ ba,
    const float* __restrict__ Wb, const float* __restrict__ bb,
    const short* __restrict__ pk, const float* __restrict__ bout,
    const float* __restrict__ bsc, float* __restrict__ out, int N, int P)
{
    __shared__ float cbuf[4][32 * 17];     // 8.7 KB total: per-wave conv, transposed

    int tid = threadIdx.x;
    int lane = tid & 63;
    int widx = __builtin_amdgcn_readfirstlane(tid >> 6);
    int n = lane & 15, g = lane >> 4;
    int wavebase = (blockIdx.x * 4 + widx) * 16;
    if (wavebase >= P) return;

    // ---- loop-invariant per-lane preloads ----
    float waX[8], waY[8], waZ[8], bav[8];
    #pragma unroll
    for (int e = 0; e < 8; ++e) {
        int k = 8 * g + e;
        waX[e] = Wa[k]; waY[e] = Wa[HID + k]; waZ[e] = Wa[2 * HID + k];
        bav[e] = ba[k];
    }
    short8 wb0, wb1;
    #pragma unroll
    for (int e = 0; e < 8; ++e) {
        int k = 8 * g + e;
        wb0[e] = bf16s(Wb[k * HID + n]);
        wb1[e] = bf16s(Wb[k * HID + 16 + n]);
    }
    float bb0 = bb[n], bb1 = bb[16 + n];
    float* cb = cbuf[widx];

    // ---- edge phase: 16 points sequentially ----
    #pragma unroll 1
    for (int pt = 0; pt < 16; ++pt) {
        int p = wavebase + pt;
        long pbase = (p >= N) ? (long)N : 0;
        float4 pp = pos4[p];

        const int* nrow = nbr + (long)p * KNB;
        // t-row edge (row = n)
        long qt = pbase + nrow[n];
        float4 pq = pos4[qt];
        float rx = pp.x - pq.x, ry = pp.y - pq.y, rz = pp.z - pq.z;

        // hg rows (D rows 4g+r), packed bf16 pairs
        long q0 = pbase + nrow[4 * g + 0];
        long q1 = pbase + nrow[4 * g + 1];
        long q2 = pbase + nrow[4 * g + 2];
        long q3 = pbase + nrow[4 * g + 3];
        unsigned v0 = h2[q0 * 16 + n];
        unsigned v1 = h2[q1 * 16 + n];
        unsigned v2 = h2[q2 * 16 + n];
        unsigned v3 = h2[q3 * 16 + n];

        // t = leaky(rel @ Wa + ba, 0.1) for this lane's 8 k-slots
        short8 af;
        #pragma unroll
        for (int e = 0; e < 8; ++e) {
            float tv = fmaf(rx, waX[e], fmaf(ry, waY[e], fmaf(rz, waZ[e], bav[e])));
            af[e] = bf16s(leaky(tv, 0.1f));
        }

        f32x4 w0 = { bb0, bb0, bb0, bb0 };
        f32x4 w1 = { bb1, bb1, bb1, bb1 };
        w0 = __builtin_amdgcn_mfma_f32_16x16x32_bf16(af, wb0, w0, 0, 0, 0);
        w1 = __builtin_amdgcn_mfma_f32_16x16x32_bf16(af, wb1, w1, 0, 0, 0);

        float hA0 = __uint_as_float(v0 << 16), hB0 = __uint_as_float(v0 & 0xffff0000u);
        float hA1 = __uint_as_float(v1 << 16), hB1 = __uint_as_float(v1 & 0xffff0000u);
        float hA2 = __uint_as_float(v2 << 16), hB2 = __uint_as_float(v2 & 0xffff0000u);
        float hA3 = __uint_as_float(v3 << 16), hB3 = __uint_as_float(v3 & 0xffff0000u);

        float pa = w0[0] * hA0 + w0[1] * hA1 + w0[2] * hA2 + w0[3] * hA3;
        float pb = w1[0] * hB0 + w1[1] * hB1 + w1[2] * hB2 + w1[3] * hB3;
        pa += __shfl_xor(pa, 16, 64);  pa += __shfl_xor(pa, 32, 64);
        pb += __shfl_xor(pb, 16, 64);  pb += __shfl_xor(pb, 32, 64);

        if (lane < 16) {
            cb[lane * 17 + pt]        = pa;   // conv[c=lane][pt]
            cb[(lane + 16) * 17 + pt] = pb;   // conv[c=lane+16][pt]
        }
    }
    asm volatile("s_waitcnt lgkmcnt(0)" ::: "memory");

    // ---- GEMV phase ----
    short8 a0, a1, a2;
    #pragma unroll
    for (int e = 0; e < 8; ++e)
        a0[e] = bf16s(cb[(8 * g + e) * 17 + n]);   // conv channels (k-step 0)
    {
        const float* xr = x + (long)(wavebase + n) * IN_C;
        float4 u0 = *(const float4*)(xr + 8 * g);
        float4 u1 = *(const float4*)(xr + 8 * g + 4);
        float4 u2 = *(const float4*)(xr + 32 + 8 * g);
        float4 u3 = *(const float4*)(xr + 32 + 8 * g + 4);
        a1[0] = bf16s(u0.x); a1[1] = bf16s(u0.y); a1[2] = bf16s(u0.z); a1[3] = bf16s(u0.w);
        a1[4] = bf16s(u1.x); a1[5] = bf16s(u1.y); a1[6] = bf16s(u1.z); a1[7] = bf16s(u1.w);
        a2[0] = bf16s(u2.x); a2[1] = bf16s(u2.y); a2[2] = bf16s(u2.z); a2[3] = bf16s(u2.w);
        a2[4] = bf16s(u3.x); a2[5] = bf16s(u3.y); a2[6] = bf16s(u3.z); a2[7] = bf16s(u3.w);
    }

    #pragma unroll 1
    for (int nt = 0; nt < 8; ++nt) {
        short8 b0 = *(const short8*)(pk + ((long)(0 * 8 + nt) * 64 + lane) * 8);
        short8 b1 = *(const short8*)(pk + ((long)(1 * 8 + nt) * 64 + lane) * 8);
        short8 b2 = *(const short8*)(pk + ((long)(2 * 8 + nt) * 64 + lane) * 8);
        int o = nt * 16 + n;
        float bv = bout[o] + bsc[o];
        f32x4 acc = { bv, bv, bv, bv };
        acc = __builtin_amdgcn_mfma_f32_16x16x32_bf16(a0, b0, acc, 0, 0, 0);
        acc = __builtin_amdgcn_mfma_f32_16x16x32_bf16(a1, b1, acc, 0, 0, 0);
        acc = __builtin_amdgcn_mfma_f32_16x16x32_bf16(a2, b2, acc, 0, 0, 0);
        #pragma unroll
        for (int r = 0; r < 4; ++r)
            out[(long)(wavebase + 4 * g + r) * OUT_C + o] = leaky(acc[r], 0.01f);
    }
}

extern "C" void kernel_launch(void* const* d_in, const int* in_sizes, int n_in,
                              void* d_out, int out_size, void* d_ws, size_t ws_size,
                              hipStream_t stream) {
    const float* x    = (const float*)d_in[0];
    const float* pos  = (const float*)d_in[1];
    const int*   nbr  = (const int*)d_in[2];
    const float* Win  = (const float*)d_in[3];
    const float* bin  = (const float*)d_in[4];
    const float* Wa   = (const float*)d_in[5];
    const float* ba   = (const float*)d_in[6];
    const float* Wb   = (const float*)d_in[7];
    const float* bb   = (const float*)d_in[8];
    const float* Wout = (const float*)d_in[9];
    const float* bout = (const float*)d_in[10];
    const float* Wsc  = (const float*)d_in[11];
    const float* bsc  = (const float*)d_in[12];
    float* out = (float*)d_out;

    int P = in_sizes[0] / IN_C;   // B*N = 131072
    int N = P / 2;                // B = 2 per reference

    // ws layout: h2 [P*16 u32] | pos4 [P float4] | pk [1536*8 shorts]
    unsigned* h2  = (unsigned*)d_ws;
    float4*  pos4 = (float4*)((char*)d_ws + (size_t)P * 64);
    short*   pk   = (short*)((char*)d_ws + (size_t)P * 64 + (size_t)P * 16);

    pack_kernel<<<(P + 255) / 256, 256, 0, stream>>>(pos, Wout, Wsc, pos4, pk, P);
    int blocks = (P + 63) / 64;   // 64 points per block (4 waves x 16)
    hid_mfma<<<blocks, 256, 0, stream>>>(x, Win, bin, h2, P);
    edgeout_mfma<<<blocks, 256, 0, stream>>>(
        x, pos4, nbr, h2, Wa, ba, Wb, bb, pk, bout, bsc, out, N, P);
}

// Round 9
// 67.277 us; speedup vs baseline: 16.2098x; 1.1100x over previous
//
#include <hip/hip_runtime.h>
#include <hip/hip_bf16.h>

#define IN_C 64
#define OUT_C 128
#define HID 32
#define KNB 16

typedef __attribute__((ext_vector_type(8))) short short8;
typedef __attribute__((ext_vector_type(4))) float f32x4;

__device__ __forceinline__ float leaky(float v, float s) { return fmaxf(v, s * v); }

__device__ __forceinline__ unsigned bf16u(float f) {
    __hip_bfloat16 h = __float2bfloat16(f);
    return (unsigned)*reinterpret_cast<unsigned short*>(&h);
}
__device__ __forceinline__ short bf16s(float f) {
    __hip_bfloat16 h = __float2bfloat16(f);
    return *reinterpret_cast<short*>(&h);
}

// ---------------- K0: one-time packs ----------------------------------------
__global__ __launch_bounds__(256) void pack_kernel(
    const float* __restrict__ pos, const float* __restrict__ Wout,
    const float* __restrict__ Wsc, float4* __restrict__ pos4,
    short* __restrict__ pk, int P)
{
    int t = blockIdx.x * 256 + threadIdx.x;
    if (t < 1536) {
        int ks = t >> 9, rem = t & 511;
        int nt = rem >> 6, g = (rem >> 4) & 3, n = rem & 15;
        int col = nt * 16 + n;
        short8 v;
        #pragma unroll
        for (int e = 0; e < 8; ++e) {
            int row = ks * 32 + 8 * g + e;
            float f = (row < 32) ? Wout[row * OUT_C + col]
                                 : Wsc[(row - 32) * OUT_C + col];
            v[e] = bf16s(f);
        }
        *(short8*)(pk + (long)t * 8) = v;
    }
    if (t < P) {
        float4 v;
        v.x = pos[3L * t + 0]; v.y = pos[3L * t + 1];
        v.z = pos[3L * t + 2]; v.w = 0.f;
        pos4[t] = v;
    }
}

// ---------------- K1: h2 = packed bf16 pair of leaky(x @ W_in + b_in) -------
__global__ __launch_bounds__(256) void hid_mfma(
    const float* __restrict__ x, const float* __restrict__ Win,
    const float* __restrict__ bin, unsigned* __restrict__ h2, int P)
{
    int lane = threadIdx.x & 63;
    int widx = __builtin_amdgcn_readfirstlane(threadIdx.x >> 6);
    int wavebase = (blockIdx.x * 4 + widx) * 16;
    if (wavebase >= P) return;
    int n = lane & 15, g = lane >> 4;

    short8 bfr[2][2];
    #pragma unroll
    for (int ks = 0; ks < 2; ++ks)
        #pragma unroll
        for (int nt = 0; nt < 2; ++nt)
            #pragma unroll
            for (int e = 0; e < 8; ++e)
                bfr[ks][nt][e] = bf16s(Win[(ks * 32 + 8 * g + e) * HID + nt * 16 + n]);

    float bv0 = bin[n], bv1 = bin[16 + n];

    const float* xr = x + (long)(wavebase + n) * IN_C;
    short8 a[2];
    #pragma unroll
    for (int ks = 0; ks < 2; ++ks) {
        float4 v0 = *(const float4*)(xr + ks * 32 + 8 * g);
        float4 v1 = *(const float4*)(xr + ks * 32 + 8 * g + 4);
        a[ks][0] = bf16s(v0.x); a[ks][1] = bf16s(v0.y);
        a[ks][2] = bf16s(v0.z); a[ks][3] = bf16s(v0.w);
        a[ks][4] = bf16s(v1.x); a[ks][5] = bf16s(v1.y);
        a[ks][6] = bf16s(v1.z); a[ks][7] = bf16s(v1.w);
    }

    f32x4 acc0 = { bv0, bv0, bv0, bv0 };
    f32x4 acc1 = { bv1, bv1, bv1, bv1 };
    acc0 = __builtin_amdgcn_mfma_f32_16x16x32_bf16(a[0], bfr[0][0], acc0, 0, 0, 0);
    acc0 = __builtin_amdgcn_mfma_f32_16x16x32_bf16(a[1], bfr[1][0], acc0, 0, 0, 0);
    acc1 = __builtin_amdgcn_mfma_f32_16x16x32_bf16(a[0], bfr[0][1], acc1, 0, 0, 0);
    acc1 = __builtin_amdgcn_mfma_f32_16x16x32_bf16(a[1], bfr[1][1], acc1, 0, 0, 0);

    #pragma unroll
    for (int r = 0; r < 4; ++r) {
        unsigned lo = bf16u(leaky(acc0[r], 0.1f));
        unsigned hi = bf16u(leaky(acc1[r], 0.1f));
        h2[(long)(wavebase + 4 * g + r) * 16 + n] = (hi << 16) | lo;
    }
}

// ---------------- K2: edge phase + output GEMV, fused, MFMA ------------------
// Block = 2 independent waves (finer dispatch); wave owns 16 points.
// amdgpu_waves_per_eu(3,4): target <=4 waves/SIMD so the allocator keeps the
// t-MLP weight invariants (40 regs) RESIDENT instead of re-loading per point
// (R8: VGPR=48 proved remat). Edge loop fully unrolled, software-pipelined:
// idx loads 2 pts ahead (int4+dword), gathers (pos4 + 4x h2) 1 pt ahead.
// x row for GEMV issued before the loop (HBM latency hidden under edge phase).
__global__ __launch_bounds__(128) __attribute__((amdgpu_waves_per_eu(3, 4)))
void edgeout_mfma(
    const float* __restrict__ x, const float4* __restrict__ pos4,
    const int* __restrict__ nbr, const unsigned* __restrict__ h2,
    const float* __restrict__ Wa, const float* __restrict__ ba,
    const float* __restrict__ Wb, const float* __restrict__ bb,
    const short* __restrict__ pk, const float* __restrict__ bout,
    const float* __restrict__ bsc, float* __restrict__ out, int N, int P)
{
    __shared__ float cbuf[2][32 * 17];     // 4.4 KB: per-wave conv, transposed

    int tid = threadIdx.x;
    int lane = tid & 63;
    int widx = __builtin_amdgcn_readfirstlane(tid >> 6);
    int n = lane & 15, g = lane >> 4;
    int wavebase = (blockIdx.x * 2 + widx) * 16;
    if (wavebase >= P) return;
    // N % 16 == 0 -> whole wave is in one batch: pbase is wave-uniform
    long pbase = (wavebase >= N) ? (long)N : 0;

    // ---- loop-invariant per-lane preloads (kept resident) ----
    float waX[8], waY[8], waZ[8], bav[8];
    #pragma unroll
    for (int e = 0; e < 8; ++e) {
        int k = 8 * g + e;
        waX[e] = Wa[k]; waY[e] = Wa[HID + k]; waZ[e] = Wa[2 * HID + k];
        bav[e] = ba[k];
    }
    short8 wb0, wb1;
    #pragma unroll
    for (int e = 0; e < 8; ++e) {
        int k = 8 * g + e;
        wb0[e] = bf16s(Wb[k * HID + n]);
        wb1[e] = bf16s(Wb[k * HID + 16 + n]);
    }
    float bb0 = bb[n], bb1 = bb[16 + n];
    float* cb = cbuf[widx];

    // ---- GEMV x-row prefetch: issue now, consume after the edge loop ----
    const float* xr = x + (long)(wavebase + n) * IN_C;
    float4 u0 = *(const float4*)(xr + 8 * g);
    float4 u1 = *(const float4*)(xr + 8 * g + 4);
    float4 u2 = *(const float4*)(xr + 32 + 8 * g);
    float4 u3 = *(const float4*)(xr + 32 + 8 * g + 4);

    // ---- edge phase: 16 points, software-pipelined, fully unrolled ----
    int4  qv[KNB]; int qs[KNB];
    float4 pp[KNB], pq[KNB];
    unsigned hv[KNB][4];

#define IDX(i) {                                                        \
        const int* nr = nbr + (long)(wavebase + (i)) * KNB;             \
        qv[i] = *(const int4*)(nr + 4 * g);                             \
        qs[i] = nr[n]; }
#define GATHER(i) {                                                     \
        pp[i] = pos4[wavebase + (i)];                                   \
        pq[i] = pos4[pbase + qs[i]];                                    \
        hv[i][0] = h2[(pbase + qv[i].x) * 16 + n];                      \
        hv[i][1] = h2[(pbase + qv[i].y) * 16 + n];                      \
        hv[i][2] = h2[(pbase + qv[i].z) * 16 + n];                      \
        hv[i][3] = h2[(pbase + qv[i].w) * 16 + n]; }

    #pragma unroll
    for (int pt = 0; pt < KNB; ++pt) {
        if (pt == 0) { IDX(0) IDX(1) GATHER(0) }
        if (pt + 2 < KNB) IDX(pt + 2)
        if (pt + 1 < KNB) GATHER(pt + 1)

        float rx = pp[pt].x - pq[pt].x;
        float ry = pp[pt].y - pq[pt].y;
        float rz = pp[pt].z - pq[pt].z;

        short8 af;
        #pragma unroll
        for (int e = 0; e < 8; ++e) {
            float tv = fmaf(rx, waX[e], fmaf(ry, waY[e], fmaf(rz, waZ[e], bav[e])));
            af[e] = bf16s(leaky(tv, 0.1f));
        }

        f32x4 w0 = { bb0, bb0, bb0, bb0 };
        f32x4 w1 = { bb1, bb1, bb1, bb1 };
        w0 = __builtin_amdgcn_mfma_f32_16x16x32_bf16(af, wb0, w0, 0, 0, 0);
        w1 = __builtin_amdgcn_mfma_f32_16x16x32_bf16(af, wb1, w1, 0, 0, 0);

        float hA0 = __uint_as_float(hv[pt][0] << 16), hB0 = __uint_as_float(hv[pt][0] & 0xffff0000u);
        float hA1 = __uint_as_float(hv[pt][1] << 16), hB1 = __uint_as_float(hv[pt][1] & 0xffff0000u);
        float hA2 = __uint_as_float(hv[pt][2] << 16), hB2 = __uint_as_float(hv[pt][2] & 0xffff0000u);
        float hA3 = __uint_as_float(hv[pt][3] << 16), hB3 = __uint_as_float(hv[pt][3] & 0xffff0000u);

        float pa = fmaf(w0[0], hA0, fmaf(w0[1], hA1, fmaf(w0[2], hA2, w0[3] * hA3)));
        float pb = fmaf(w1[0], hB0, fmaf(w1[1], hB1, fmaf(w1[2], hB2, w1[3] * hB3)));
        pa += __shfl_xor(pa, 16, 64);  pa += __shfl_xor(pa, 32, 64);
        pb += __shfl_xor(pb, 16, 64);  pb += __shfl_xor(pb, 32, 64);

        // after the xor-reduce every lane holds the full sums; spread the
        // transposed store across groups g=0 (low 16 ch) and g=1 (high 16 ch)
        if (g == 0)      cb[n * 17 + pt]        = pa;
        else if (g == 1) cb[(n + 16) * 17 + pt] = pb;
    }
#undef IDX
#undef GATHER

    asm volatile("s_waitcnt lgkmcnt(0)" ::: "memory");

    // ---- GEMV phase ----
    short8 a0, a1, a2;
    #pragma unroll
    for (int e = 0; e < 8; ++e)
        a0[e] = bf16s(cb[(8 * g + e) * 17 + n]);   // conv channels (k-step 0)
    a1[0] = bf16s(u0.x); a1[1] = bf16s(u0.y); a1[2] = bf16s(u0.z); a1[3] = bf16s(u0.w);
    a1[4] = bf16s(u1.x); a1[5] = bf16s(u1.y); a1[6] = bf16s(u1.z); a1[7] = bf16s(u1.w);
    a2[0] = bf16s(u2.x); a2[1] = bf16s(u2.y); a2[2] = bf16s(u2.z); a2[3] = bf16s(u2.w);
    a2[4] = bf16s(u3.x); a2[5] = bf16s(u3.y); a2[6] = bf16s(u3.z); a2[7] = bf16s(u3.w);

    #pragma unroll 2
    for (int nt = 0; nt < 8; ++nt) {
        short8 b0 = *(const short8*)(pk + ((long)(0 * 8 + nt) * 64 + lane) * 8);
        short8 b1 = *(const short8*)(pk + ((long)(1 * 8 + nt) * 64 + lane) * 8);
        short8 b2 = *(const short8*)(pk + ((long)(2 * 8 + nt) * 64 + lane) * 8);
        int o = nt * 16 + n;
        float bv = bout[o] + bsc[o];
        f32x4 acc = { bv, bv, bv, bv };
        acc = __builtin_amdgcn_mfma_f32_16x16x32_bf16(a0, b0, acc, 0, 0, 0);
        acc = __builtin_amdgcn_mfma_f32_16x16x32_bf16(a1, b1, acc, 0, 0, 0);
        acc = __builtin_amdgcn_mfma_f32_16x16x32_bf16(a2, b2, acc, 0, 0, 0);
        #pragma unroll
        for (int r = 0; r < 4; ++r)
            out[(long)(wavebase + 4 * g + r) * OUT_C + o] = leaky(acc[r], 0.01f);
    }
}

extern "C" void kernel_launch(void* const* d_in, const int* in_sizes, int n_in,
                              void* d_out, int out_size, void* d_ws, size_t ws_size,
                              hipStream_t stream) {
    const float* x    = (const float*)d_in[0];
    const float* pos  = (const float*)d_in[1];
    const int*   nbr  = (const int*)d_in[2];
    const float* Win  = (const float*)d_in[3];
    const float* bin  = (const float*)d_in[4];
    const float* Wa   = (const float*)d_in[5];
    const float* ba   = (const float*)d_in[6];
    const float* Wb   = (const float*)d_in[7];
    const float* bb   = (const float*)d_in[8];
    const float* Wout = (const float*)d_in[9];
    const float* bout = (const float*)d_in[10];
    const float* Wsc  = (const float*)d_in[11];
    const float* bsc  = (const float*)d_in[12];
    float* out = (float*)d_out;

    int P = in_sizes[0] / IN_C;   // B*N = 131072
    int N = P / 2;                // B = 2 per reference

    // ws layout: h2 [P*16 u32] | pos4 [P float4] | pk [1536*8 shorts]
    unsigned* h2  = (unsigned*)d_ws;
    float4*  pos4 = (float4*)((char*)d_ws + (size_t)P * 64);
    short*   pk   = (short*)((char*)d_ws + (size_t)P * 64 + (size_t)P * 16);

    pack_kernel<<<(P + 255) / 256, 256, 0, stream>>>(pos, Wout, Wsc, pos4, pk, P);
    hid_mfma<<<(P + 63) / 64, 256, 0, stream>>>(x, Win, bin, h2, P);
    edgeout_mfma<<<(P + 31) / 32, 128, 0, stream>>>(
        x, pos4, nbr, h2, Wa, ba, Wb, bb, pk, bout, bsc, out, N, P);
}

// Round 10
// 63.610 us; speedup vs baseline: 17.1445x; 1.0577x over previous
//
#include <hip/hip_runtime.h>
#include <hip/hip_bf16.h>

#define IN_C 64
#define OUT_C 128
#define HID 32
#define KNB 16

typedef __attribute__((ext_vector_type(8))) short short8;
typedef __attribute__((ext_vector_type(4))) float f32x4;

__device__ __forceinline__ float leaky(float v, float s) { return fmaxf(v, s * v); }

__device__ __forceinline__ unsigned bf16u(float f) {
    __hip_bfloat16 h = __float2bfloat16(f);
    return (unsigned)*reinterpret_cast<unsigned short*>(&h);
}
__device__ __forceinline__ short bf16s(float f) {
    __hip_bfloat16 h = __float2bfloat16(f);
    return *reinterpret_cast<short*>(&h);
}

// ---------------- K1: h2 pack + pos4 pack + weight pack (fused) -------------
// Wave handles 16 points for h2 = packed bf16 pair of leaky(x@W_in + b_in).
// Side duties (independent lanes): pos4 copy (tg < P), pk pack (tg < 1536).
__global__ __launch_bounds__(256) void hid_mfma(
    const float* __restrict__ x, const float* __restrict__ Win,
    const float* __restrict__ bin, const float* __restrict__ pos,
    const float* __restrict__ Wout, const float* __restrict__ Wsc,
    unsigned* __restrict__ h2, float4* __restrict__ pos4,
    short* __restrict__ pk, int P)
{
    int tg = blockIdx.x * 256 + (int)threadIdx.x;   // 4P total threads

    // ---- side duty 1: pos4 copy (first P threads) ----
    if (tg < P) {
        float4 v;
        v.x = pos[3L * tg + 0]; v.y = pos[3L * tg + 1];
        v.z = pos[3L * tg + 2]; v.w = 0.f;
        pos4[tg] = v;
    }
    // ---- side duty 2: [Wout;Wsc] bf16 chunk pack (first 1536 threads) ----
    if (tg < 1536) {
        int ks = tg >> 9, rem = tg & 511;
        int nt = rem >> 6, g2 = (rem >> 4) & 3, n2 = rem & 15;
        int col = nt * 16 + n2;
        short8 v;
        #pragma unroll
        for (int e = 0; e < 8; ++e) {
            int row = ks * 32 + 8 * g2 + e;
            float f = (row < 32) ? Wout[row * OUT_C + col]
                                 : Wsc[(row - 32) * OUT_C + col];
            v[e] = bf16s(f);
        }
        *(short8*)(pk + (long)tg * 8) = v;
    }

    int lane = threadIdx.x & 63;
    int widx = __builtin_amdgcn_readfirstlane(threadIdx.x >> 6);
    int wavebase = (blockIdx.x * 4 + widx) * 16;
    if (wavebase >= P) return;
    int n = lane & 15, g = lane >> 4;

    short8 bfr[2][2];
    #pragma unroll
    for (int ks = 0; ks < 2; ++ks)
        #pragma unroll
        for (int nt = 0; nt < 2; ++nt)
            #pragma unroll
            for (int e = 0; e < 8; ++e)
                bfr[ks][nt][e] = bf16s(Win[(ks * 32 + 8 * g + e) * HID + nt * 16 + n]);

    float bv0 = bin[n], bv1 = bin[16 + n];

    const float* xr = x + (long)(wavebase + n) * IN_C;
    short8 a[2];
    #pragma unroll
    for (int ks = 0; ks < 2; ++ks) {
        float4 v0 = *(const float4*)(xr + ks * 32 + 8 * g);
        float4 v1 = *(const float4*)(xr + ks * 32 + 8 * g + 4);
        a[ks][0] = bf16s(v0.x); a[ks][1] = bf16s(v0.y);
        a[ks][2] = bf16s(v0.z); a[ks][3] = bf16s(v0.w);
        a[ks][4] = bf16s(v1.x); a[ks][5] = bf16s(v1.y);
        a[ks][6] = bf16s(v1.z); a[ks][7] = bf16s(v1.w);
    }

    f32x4 acc0 = { bv0, bv0, bv0, bv0 };
    f32x4 acc1 = { bv1, bv1, bv1, bv1 };
    acc0 = __builtin_amdgcn_mfma_f32_16x16x32_bf16(a[0], bfr[0][0], acc0, 0, 0, 0);
    acc0 = __builtin_amdgcn_mfma_f32_16x16x32_bf16(a[1], bfr[1][0], acc0, 0, 0, 0);
    acc1 = __builtin_amdgcn_mfma_f32_16x16x32_bf16(a[0], bfr[0][1], acc1, 0, 0, 0);
    acc1 = __builtin_amdgcn_mfma_f32_16x16x32_bf16(a[1], bfr[1][1], acc1, 0, 0, 0);

    #pragma unroll
    for (int r = 0; r < 4; ++r) {
        unsigned lo = bf16u(leaky(acc0[r], 0.1f));
        unsigned hi = bf16u(leaky(acc1[r], 0.1f));
        h2[(long)(wavebase + 4 * g + r) * 16 + n] = (hi << 16) | lo;
    }
}

// ---------------- K2: edge phase + output GEMV, fused, MFMA ------------------
// Block = 2 independent waves; wave owns 16 points. Deep software pipeline:
// idx loads 3 pts ahead, gathers (pos4 + 4x h2) 2 pts ahead (~2 compute
// bodies of latency cover). x row for GEMV issued before the edge loop.
__global__ __launch_bounds__(128)
void edgeout_mfma(
    const float* __restrict__ x, const float4* __restrict__ pos4,
    const int* __restrict__ nbr, const unsigned* __restrict__ h2,
    const float* __restrict__ Wa, const float* __restrict__ ba,
    const float* __restrict__ Wb, const float* __restrict__ bb,
    const short* __restrict__ pk, const float* __restrict__ bout,
    const float* __restrict__ bsc, float* __restrict__ out, int N, int P)
{
    __shared__ float cbuf[2][32 * 17];     // 4.4 KB: per-wave conv, transposed

    int tid = threadIdx.x;
    int lane = tid & 63;
    int widx = __builtin_amdgcn_readfirstlane(tid >> 6);
    int n = lane & 15, g = lane >> 4;
    int wavebase = (blockIdx.x * 2 + widx) * 16;
    if (wavebase >= P) return;
    // N % 16 == 0 -> whole wave is in one batch: pbase is wave-uniform
    long pbase = (wavebase >= N) ? (long)N : 0;

    // ---- loop-invariant per-lane preloads ----
    float waX[8], waY[8], waZ[8], bav[8];
    #pragma unroll
    for (int e = 0; e < 8; ++e) {
        int k = 8 * g + e;
        waX[e] = Wa[k]; waY[e] = Wa[HID + k]; waZ[e] = Wa[2 * HID + k];
        bav[e] = ba[k];
    }
    short8 wb0, wb1;
    #pragma unroll
    for (int e = 0; e < 8; ++e) {
        int k = 8 * g + e;
        wb0[e] = bf16s(Wb[k * HID + n]);
        wb1[e] = bf16s(Wb[k * HID + 16 + n]);
    }
    float bb0 = bb[n], bb1 = bb[16 + n];
    float* cb = cbuf[widx];

    // ---- GEMV x-row prefetch: issue now, consume after the edge loop ----
    const float* xr = x + (long)(wavebase + n) * IN_C;
    float4 u0 = *(const float4*)(xr + 8 * g);
    float4 u1 = *(const float4*)(xr + 8 * g + 4);
    float4 u2 = *(const float4*)(xr + 32 + 8 * g);
    float4 u3 = *(const float4*)(xr + 32 + 8 * g + 4);

    // ---- edge phase: 16 points, software-pipelined, fully unrolled ----
    int4  qv[KNB]; int qs[KNB];
    float4 pp[KNB], pq[KNB];
    unsigned hv[KNB][4];

#define IDX(i) {                                                        \
        const int* nr = nbr + (long)(wavebase + (i)) * KNB;             \
        qv[i] = *(const int4*)(nr + 4 * g);                             \
        qs[i] = nr[n]; }
#define GATHER(i) {                                                     \
        pp[i] = pos4[wavebase + (i)];                                   \
        pq[i] = pos4[pbase + qs[i]];                                    \
        hv[i][0] = h2[(pbase + qv[i].x) * 16 + n];                      \
        hv[i][1] = h2[(pbase + qv[i].y) * 16 + n];                      \
        hv[i][2] = h2[(pbase + qv[i].z) * 16 + n];                      \
        hv[i][3] = h2[(pbase + qv[i].w) * 16 + n]; }

    #pragma unroll
    for (int pt = 0; pt < KNB; ++pt) {
        if (pt == 0) { IDX(0) IDX(1) IDX(2) GATHER(0) GATHER(1) }
        if (pt + 3 < KNB) IDX(pt + 3)
        if (pt + 2 < KNB) GATHER(pt + 2)

        float rx = pp[pt].x - pq[pt].x;
        float ry = pp[pt].y - pq[pt].y;
        float rz = pp[pt].z - pq[pt].z;

        short8 af;
        #pragma unroll
        for (int e = 0; e < 8; ++e) {
            float tv = fmaf(rx, waX[e], fmaf(ry, waY[e], fmaf(rz, waZ[e], bav[e])));
            af[e] = bf16s(leaky(tv, 0.1f));
        }

        f32x4 w0 = { bb0, bb0, bb0, bb0 };
        f32x4 w1 = { bb1, bb1, bb1, bb1 };
        w0 = __builtin_amdgcn_mfma_f32_16x16x32_bf16(af, wb0, w0, 0, 0, 0);
        w1 = __builtin_amdgcn_mfma_f32_16x16x32_bf16(af, wb1, w1, 0, 0, 0);

        float hA0 = __uint_as_float(hv[pt][0] << 16), hB0 = __uint_as_float(hv[pt][0] & 0xffff0000u);
        float hA1 = __uint_as_float(hv[pt][1] << 16), hB1 = __uint_as_float(hv[pt][1] & 0xffff0000u);
        float hA2 = __uint_as_float(hv[pt][2] << 16), hB2 = __uint_as_float(hv[pt][2] & 0xffff0000u);
        float hA3 = __uint_as_float(hv[pt][3] << 16), hB3 = __uint_as_float(hv[pt][3] & 0xffff0000u);

        float pa = fmaf(w0[0], hA0, fmaf(w0[1], hA1, fmaf(w0[2], hA2, w0[3] * hA3)));
        float pb = fmaf(w1[0], hB0, fmaf(w1[1], hB1, fmaf(w1[2], hB2, w1[3] * hB3)));
        pa += __shfl_xor(pa, 16, 64);  pa += __shfl_xor(pa, 32, 64);
        pb += __shfl_xor(pb, 16, 64);  pb += __shfl_xor(pb, 32, 64);

        if (g == 0)      cb[n * 17 + pt]        = pa;
        else if (g == 1) cb[(n + 16) * 17 + pt] = pb;
    }
#undef IDX
#undef GATHER

    asm volatile("s_waitcnt lgkmcnt(0)" ::: "memory");

    // ---- GEMV phase ----
    short8 a0, a1, a2;
    #pragma unroll
    for (int e = 0; e < 8; ++e)
        a0[e] = bf16s(cb[(8 * g + e) * 17 + n]);   // conv channels (k-step 0)
    a1[0] = bf16s(u0.x); a1[1] = bf16s(u0.y); a1[2] = bf16s(u0.z); a1[3] = bf16s(u0.w);
    a1[4] = bf16s(u1.x); a1[5] = bf16s(u1.y); a1[6] = bf16s(u1.z); a1[7] = bf16s(u1.w);
    a2[0] = bf16s(u2.x); a2[1] = bf16s(u2.y); a2[2] = bf16s(u2.z); a2[3] = bf16s(u2.w);
    a2[4] = bf16s(u3.x); a2[5] = bf16s(u3.y); a2[6] = bf16s(u3.z); a2[7] = bf16s(u3.w);

    #pragma unroll 2
    for (int nt = 0; nt < 8; ++nt) {
        short8 b0 = *(const short8*)(pk + ((long)(0 * 8 + nt) * 64 + lane) * 8);
        short8 b1 = *(const short8*)(pk + ((long)(1 * 8 + nt) * 64 + lane) * 8);
        short8 b2 = *(const short8*)(pk + ((long)(2 * 8 + nt) * 64 + lane) * 8);
        int o = nt * 16 + n;
        float bv = bout[o] + bsc[o];
        f32x4 acc = { bv, bv, bv, bv };
        acc = __builtin_amdgcn_mfma_f32_16x16x32_bf16(a0, b0, acc, 0, 0, 0);
        acc = __builtin_amdgcn_mfma_f32_16x16x32_bf16(a1, b1, acc, 0, 0, 0);
        acc = __builtin_amdgcn_mfma_f32_16x16x32_bf16(a2, b2, acc, 0, 0, 0);
        #pragma unroll
        for (int r = 0; r < 4; ++r)
            out[(long)(wavebase + 4 * g + r) * OUT_C + o] = leaky(acc[r], 0.01f);
    }
}

extern "C" void kernel_launch(void* const* d_in, const int* in_sizes, int n_in,
                              void* d_out, int out_size, void* d_ws, size_t ws_size,
                              hipStream_t stream) {
    const float* x    = (const float*)d_in[0];
    const float* pos  = (const float*)d_in[1];
    const int*   nbr  = (const int*)d_in[2];
    const float* Win  = (const float*)d_in[3];
    const float* bin  = (const float*)d_in[4];
    const float* Wa   = (const float*)d_in[5];
    const float* ba   = (const float*)d_in[6];
    const float* Wb   = (const float*)d_in[7];
    const float* bb   = (const float*)d_in[8];
    const float* Wout = (const float*)d_in[9];
    const float* bout = (const float*)d_in[10];
    const float* Wsc  = (const float*)d_in[11];
    const float* bsc  = (const float*)d_in[12];
    float* out = (float*)d_out;

    int P = in_sizes[0] / IN_C;   // B*N = 131072
    int N = P / 2;                // B = 2 per reference

    // ws layout: h2 [P*16 u32] | pos4 [P float4] | pk [1536*8 shorts]
    unsigned* h2  = (unsigned*)d_ws;
    float4*  pos4 = (float4*)((char*)d_ws + (size_t)P * 64);
    short*   pk   = (short*)((char*)d_ws + (size_t)P * 64 + (size_t)P * 16);

    hid_mfma<<<(P + 63) / 64, 256, 0, stream>>>(
        x, Win, bin, pos, Wout, Wsc, h2, pos4, pk, P);
    edgeout_mfma<<<(P + 31) / 32, 128, 0, stream>>>(
        x, pos4, nbr, h2, Wa, ba, Wb, bb, pk, bout, bsc, out, N, P);
}